// Round 1
// baseline (277.138 us; speedup 1.0000x reference)
//
#include <hip/hip_runtime.h>
#include <hip/hip_bf16.h>
#include <math.h>

#define NN 2048

typedef __bf16 bf16x8 __attribute__((ext_vector_type(8)));
typedef float  f32x4  __attribute__((ext_vector_type(4)));

__device__ __forceinline__ unsigned fkey(float f){
  unsigned u = __float_as_uint(f);
  return (u & 0x80000000u) ? ~u : (u | 0x80000000u);
}
__device__ __forceinline__ float funkey(unsigned k){
  unsigned u = (k & 0x80000000u) ? (k ^ 0x80000000u) : ~k;
  return __uint_as_float(u);
}

// ---------------- encode + qkv(iter1) + zero row-max arrays ----------------
__global__ void k_encqkv(const float* __restrict__ x, const float* __restrict__ comms,
    const float* __restrict__ Wenc, const float* __restrict__ benc,
    const float* __restrict__ Wq, const float* __restrict__ bq,
    const float* __restrict__ Wk, const float* __restrict__ bk,
    const float* __restrict__ Wv, const float* __restrict__ bv,
    float* __restrict__ h, float* __restrict__ q, float* __restrict__ kk, float* __restrict__ v,
    unsigned* __restrict__ M1, unsigned* __restrict__ M2)
{
  int t = threadIdx.x, b = blockIdx.x;
  if (t < 8){ M1[b*8+t] = 0u; M2[b*8+t] = 0u; }
  int r = t >> 5, c = t & 31;
  int row = b*8 + r;
  float acc = benc[c];
  #pragma unroll
  for (int d=0; d<8; ++d) acc = fmaf(x[row*8+d],     Wenc[d*32+c],     acc);
  #pragma unroll
  for (int d=0; d<8; ++d) acc = fmaf(comms[row*8+d], Wenc[(8+d)*32+c], acc);
  __shared__ float hs[8][32];
  hs[r][c] = acc;
  h[row*32+c] = acc;
  __syncthreads();
  float aq=bq[c], ak=bk[c], av=bv[c];
  #pragma unroll 8
  for (int d=0; d<32; ++d){
    float hv = hs[r][d];
    aq = fmaf(hv, Wq[d*32+c], aq);
    ak = fmaf(hv, Wk[d*32+c], ak);
    av = fmaf(hv, Wv[d*32+c], av);
  }
  q[row*32+c]=aq; kk[row*32+c]=ak; v[row*32+c]=av;
}

// ---------------- pairwise-MLP logits: one 16x16 (i,j) tile per wave ----------------
__launch_bounds__(256)
__global__ void k_logits(const float* __restrict__ q, const float* __restrict__ kk,
    const float* __restrict__ adj, const float* __restrict__ dense,
    const float* __restrict__ W1, const float* __restrict__ b1,
    const float* __restrict__ W2, const float* __restrict__ b2,
    const float* __restrict__ W3, const float* __restrict__ b3,
    float* __restrict__ logits, unsigned* __restrict__ M)
{
  int t = threadIdx.x;
  int wave = t >> 6;
  int l = t & 63;
  int lj = l & 15, g = l >> 4;
  int j0 = blockIdx.x * 64 + wave * 16;   // j fast dim: co-scheduled blocks share adj rows
  int i0 = blockIdx.y * 16;
  int c1b = 8*g;

  // dots = kk @ q^T on this 16x16 tile.  A = kk rows (i), B[k][j] = q[j][k].
  const f32x4* kp = (const f32x4*)(kk + (i0+lj)*32 + c1b);
  f32x4 k0 = kp[0], k1 = kp[1];
  const f32x4* qp = (const f32x4*)(q + (j0+lj)*32 + c1b);
  f32x4 q0 = qp[0], q1 = qp[1];
  bf16x8 af, bq8;
  #pragma unroll
  for (int e=0;e<4;++e){
    af[e] = (__bf16)k0[e];  af[4+e] = (__bf16)k1[e];
    bq8[e] = (__bf16)q0[e]; bq8[4+e] = (__bf16)q1[e];
  }
  f32x4 dacc = {0.f,0.f,0.f,0.f};
  dacc = __builtin_amdgcn_mfma_f32_16x16x32_bf16(af, bq8, dacc, 0, 0, 0);
  // dacc[r] = dots[i0+4g+r][j0+lj]  (verified C/D layout)

  // per-lane weight slices
  f32x4 w10a = *(const f32x4*)(W1 + c1b);      f32x4 w10b = *(const f32x4*)(W1 + c1b + 4);
  f32x4 w11a = *(const f32x4*)(W1 + 32 + c1b); f32x4 w11b = *(const f32x4*)(W1 + 32 + c1b + 4);
  f32x4 w12a = *(const f32x4*)(W1 + 64 + c1b); f32x4 w12b = *(const f32x4*)(W1 + 64 + c1b + 4);
  f32x4 b1a  = *(const f32x4*)(b1 + c1b);      f32x4 b1b  = *(const f32x4*)(b1 + c1b + 4);
  bf16x8 w2f0, w2f1;   // B-frags for f2 = f1 @ W2 (two N-halves)
  #pragma unroll
  for (int e=0;e<8;++e){
    w2f0[e] = (__bf16)W2[(c1b+e)*32 + lj];
    w2f1[e] = (__bf16)W2[(c1b+e)*32 + 16 + lj];
  }
  float b2A = b2[lj], b2B = b2[16+lj];
  float w3A = W3[lj], w3B = W3[16+lj];
  float b3v = b3[0];

  float adjv[16], denv[16];
  #pragma unroll
  for (int m=0;m<16;++m){
    adjv[m] = adj  [(i0+m)*NN + j0 + lj];
    denv[m] = dense[(i0+m)*NN + j0 + lj];
  }

  #pragma unroll
  for (int m=0;m<16;++m){
    // broadcast dots[i0+m][j0+lj] to all 4 k-groups
    float d = __shfl(dacc[m & 3], ((m >> 2) << 4) + lj, 64);
    // f1 = relu(feats @ W1 + b1), this lane's 8-c1 slice, for pair (m, lj)
    bf16x8 f1f;
    #pragma unroll
    for (int e=0;e<4;++e){
      float fa = fmaf(d, w10a[e], fmaf(adjv[m], w11a[e], fmaf(denv[m], w12a[e], b1a[e])));
      f1f[e]   = (__bf16)fmaxf(fa, 0.f);
      float fb = fmaf(d, w10b[e], fmaf(adjv[m], w11b[e], fmaf(denv[m], w12b[e], b1b[e])));
      f1f[4+e] = (__bf16)fmaxf(fb, 0.f);
    }
    f32x4 z = {0.f,0.f,0.f,0.f};
    f32x4 a0 = __builtin_amdgcn_mfma_f32_16x16x32_bf16(f1f, w2f0, z, 0,0,0);
    f32x4 a1 = __builtin_amdgcn_mfma_f32_16x16x32_bf16(f1f, w2f1, z, 0,0,0);
    // logit partials: relu(f2+b2) . W3  (this lane covers c2 = lj and 16+lj)
    float t0 = fmaxf(a0[0]+b2A,0.f)*w3A + fmaxf(a1[0]+b2B,0.f)*w3B;
    float t1 = fmaxf(a0[1]+b2A,0.f)*w3A + fmaxf(a1[1]+b2B,0.f)*w3B;
    float t2 = fmaxf(a0[2]+b2A,0.f)*w3A + fmaxf(a1[2]+b2B,0.f)*w3B;
    float t3 = fmaxf(a0[3]+b2A,0.f)*w3A + fmaxf(a1[3]+b2B,0.f)*w3B;
    #pragma unroll
    for (int mk=1; mk<16; mk<<=1){
      t0 += __shfl_xor(t0, mk, 64);
      t1 += __shfl_xor(t1, mk, 64);
      t2 += __shfl_xor(t2, mk, 64);
      t3 += __shfl_xor(t3, mk, 64);
    }
    t0 += b3v; t1 += b3v; t2 += b3v; t3 += b3v;
    // store: lane (16g + lj), lj<4 stores logits[i0+m][j0 + 4g + lj] = t[lj]
    float s01 = (lj & 1) ? t1 : t0;
    float s23 = (lj & 1) ? t3 : t2;
    float sv  = (lj & 2) ? s23 : s01;
    if (lj < 4) logits[(i0+m)*NN + j0 + 4*g + lj] = sv;
    // tile row-max -> global atomic row-max (order-independent)
    float mx = fmaxf(fmaxf(t0,t1), fmaxf(t2,t3));
    mx = fmaxf(mx, __shfl_xor(mx, 16, 64));
    mx = fmaxf(mx, __shfl_xor(mx, 32, 64));
    if (l == 0) atomicMax(&M[i0+m], fkey(mx));
  }
}

// ---------------- softmax + focus@v + residual (+ fused qkv-next or decode) ----------------
template<int LAST>
__launch_bounds__(256)
__global__ void k_pv(const float* __restrict__ logits, const unsigned* __restrict__ M,
    const float* __restrict__ v, const float* __restrict__ h_in,
    float* __restrict__ h_out,
    const float* __restrict__ Wq, const float* __restrict__ bq,
    const float* __restrict__ Wk, const float* __restrict__ bk,
    const float* __restrict__ Wv, const float* __restrict__ bv,
    float* __restrict__ qn, float* __restrict__ kn, float* __restrict__ vn,
    const float* __restrict__ Wdec, const float* __restrict__ bdec,
    const float* __restrict__ mask, float* __restrict__ out)
{
  int t = threadIdx.x;
  int w = t >> 6;
  int l = t & 63;
  int li = l & 15, g = l >> 4;
  int i0 = blockIdx.x * 16;
  float Mrow = funkey(M[i0 + li]);
  f32x4 acc0 = {0.f,0.f,0.f,0.f}, acc1 = {0.f,0.f,0.f,0.f};
  float Lp = 0.f;
  int jw = w * 512;
  const float* lrow = logits + (i0+li)*NN + jw + 8*g;
  for (int s=0; s<16; ++s){
    int jb = jw + s*32 + 8*g;
    f32x4 p0 = *(const f32x4*)(lrow + s*32);
    f32x4 p1 = *(const f32x4*)(lrow + s*32 + 4);
    bf16x8 pf;
    #pragma unroll
    for (int e=0;e<4;++e){
      float e0 = __expf(p0[e] - Mrow);
      __bf16 r0 = (__bf16)e0; pf[e]   = r0; Lp += (float)r0;  // sum the rounded p
      float e1 = __expf(p1[e] - Mrow);
      __bf16 r1 = (__bf16)e1; pf[4+e] = r1; Lp += (float)r1;
    }
    bf16x8 vf0, vf1;
    #pragma unroll
    for (int e=0;e<8;++e){
      vf0[e] = (__bf16)v[(jb+e)*32 + li];
      vf1[e] = (__bf16)v[(jb+e)*32 + 16 + li];
    }
    acc0 = __builtin_amdgcn_mfma_f32_16x16x32_bf16(pf, vf0, acc0, 0,0,0);
    acc1 = __builtin_amdgcn_mfma_f32_16x16x32_bf16(pf, vf1, acc1, 0,0,0);
  }
  Lp += __shfl_xor(Lp, 16, 64);
  Lp += __shfl_xor(Lp, 32, 64);
  __shared__ float accs[4][16][32];
  __shared__ float Ls[4][16];
  __shared__ float hsn[16][32];
  #pragma unroll
  for (int r=0;r<4;++r){
    accs[w][4*g+r][li]    = acc0[r];
    accs[w][4*g+r][16+li] = acc1[r];
  }
  if (l < 16) Ls[w][l] = Lp;
  __syncthreads();
  for (int o = t; o < 512; o += 256){
    int i = o >> 5, c = o & 31;
    float s4 = accs[0][i][c] + accs[1][i][c] + accs[2][i][c] + accs[3][i][c];
    float L4 = Ls[0][i] + Ls[1][i] + Ls[2][i] + Ls[3][i];
    float hnew = h_in[(i0+i)*32 + c] + s4 / L4;
    hsn[i][c] = hnew;
    if (!LAST) h_out[(i0+i)*32+c] = hnew;
  }
  __syncthreads();
  if (!LAST){
    for (int o = t; o < 512; o += 256){
      int i = o >> 5, c = o & 31;
      float aq = bq[c], ak = bk[c], av = bv[c];
      #pragma unroll 8
      for (int d=0; d<32; ++d){
        float hv = hsn[i][d];
        aq = fmaf(hv, Wq[d*32+c], aq);
        ak = fmaf(hv, Wk[d*32+c], ak);
        av = fmaf(hv, Wv[d*32+c], av);
      }
      qn[(i0+i)*32+c] = aq; kn[(i0+i)*32+c] = ak; vn[(i0+i)*32+c] = av;
    }
  } else {
    __shared__ float red[16][16];
    int ii = t >> 4, cs = t & 15;
    float part = hsn[ii][2*cs]*Wdec[2*cs] + hsn[ii][2*cs+1]*Wdec[2*cs+1];
    red[ii][cs] = part;
    __syncthreads();
    if (t < 16){
      float sacc = 0.f;
      #pragma unroll
      for (int e=0;e<16;++e) sacc += red[t][e];
      float o = sacc + bdec[0];
      float mk = mask[i0+t];
      out[i0+t] = o + (mk == 0.f ? -INFINITY : 0.f);
    }
  }
}

extern "C" void kernel_launch(void* const* d_in, const int* in_sizes, int n_in,
                              void* d_out, int out_size, void* d_ws, size_t ws_size,
                              hipStream_t stream)
{
  const float* x     = (const float*)d_in[0];
  const float* comms = (const float*)d_in[1];
  const float* adj   = (const float*)d_in[2];
  const float* dense = (const float*)d_in[3];
  const float* mask  = (const float*)d_in[4];
  const float* Wenc  = (const float*)d_in[5];
  const float* benc  = (const float*)d_in[6];
  const float* Wq    = (const float*)d_in[7];
  const float* bq    = (const float*)d_in[8];
  const float* Wk    = (const float*)d_in[9];
  const float* bk    = (const float*)d_in[10];
  const float* Wv    = (const float*)d_in[11];
  const float* bv    = (const float*)d_in[12];
  const float* W1    = (const float*)d_in[13];
  const float* b1    = (const float*)d_in[14];
  const float* W2    = (const float*)d_in[15];
  const float* b2    = (const float*)d_in[16];
  const float* W3    = (const float*)d_in[17];
  const float* b3    = (const float*)d_in[18];
  const float* Wdec  = (const float*)d_in[19];
  const float* bdec  = (const float*)d_in[20];
  float* out = (float*)d_out;

  // workspace carve (~18.9 MB)
  float* logits = (float*)d_ws;
  float* h1 = logits + (size_t)NN*NN;
  float* h2 = h1 + NN*32;
  float* q1 = h2 + NN*32;
  float* k1 = q1 + NN*32;
  float* v1 = k1 + NN*32;
  float* q2 = v1 + NN*32;
  float* k2 = q2 + NN*32;
  float* v2 = k2 + NN*32;
  unsigned* M1 = (unsigned*)(v2 + NN*32);
  unsigned* M2 = M1 + NN;

  k_encqkv<<<256, 256, 0, stream>>>(x, comms, Wenc, benc, Wq,bq,Wk,bk,Wv,bv,
                                    h1, q1, k1, v1, M1, M2);
  dim3 gl(32, 128);
  k_logits<<<gl, 256, 0, stream>>>(q1, k1, adj, dense, W1,b1,W2,b2,W3,b3, logits, M1);
  k_pv<0><<<128, 256, 0, stream>>>(logits, M1, v1, h1, h2,
                                   Wq,bq,Wk,bk,Wv,bv, q2,k2,v2,
                                   nullptr, nullptr, nullptr, nullptr);
  k_logits<<<gl, 256, 0, stream>>>(q2, k2, adj, dense, W1,b1,W2,b2,W3,b3, logits, M2);
  k_pv<1><<<128, 256, 0, stream>>>(logits, M2, v2, h2, nullptr,
                                   nullptr,nullptr,nullptr,nullptr,nullptr,nullptr,
                                   nullptr,nullptr,nullptr,
                                   Wdec, bdec, mask, out);
}

// Round 2
// 120.263 us; speedup vs baseline: 2.3044x; 2.3044x over previous
//
#include <hip/hip_runtime.h>
#include <hip/hip_bf16.h>
#include <math.h>

#define NN 2048

typedef __bf16 bf16x8 __attribute__((ext_vector_type(8)));
typedef float  f32x4  __attribute__((ext_vector_type(4)));

// ---------------- encode + qkv(iter1) ----------------
__global__ void k_encqkv(const float* __restrict__ x, const float* __restrict__ comms,
    const float* __restrict__ Wenc, const float* __restrict__ benc,
    const float* __restrict__ Wq, const float* __restrict__ bq,
    const float* __restrict__ Wk, const float* __restrict__ bk,
    const float* __restrict__ Wv, const float* __restrict__ bv,
    float* __restrict__ h, float* __restrict__ q, float* __restrict__ kk, float* __restrict__ v)
{
  int t = threadIdx.x, b = blockIdx.x;
  int r = t >> 5, c = t & 31;
  int row = b*8 + r;
  float acc = benc[c];
  #pragma unroll
  for (int d=0; d<8; ++d) acc = fmaf(x[row*8+d],     Wenc[d*32+c],     acc);
  #pragma unroll
  for (int d=0; d<8; ++d) acc = fmaf(comms[row*8+d], Wenc[(8+d)*32+c], acc);
  __shared__ float hs[8][32];
  hs[r][c] = acc;
  h[row*32+c] = acc;
  __syncthreads();
  float aq=bq[c], ak=bk[c], av=bv[c];
  #pragma unroll 8
  for (int d=0; d<32; ++d){
    float hv = hs[r][d];
    aq = fmaf(hv, Wq[d*32+c], aq);
    ak = fmaf(hv, Wk[d*32+c], ak);
    av = fmaf(hv, Wv[d*32+c], av);
  }
  q[row*32+c]=aq; kk[row*32+c]=ak; v[row*32+c]=av;
}

// ---------------- pairwise-MLP logits: one 16x16 (i,j) tile per wave ----------------
// Operand-swapped W2 MFMA: D[c2][pair] so the W3 reduction is lane-local.
__launch_bounds__(256)
__global__ void k_logits(const float* __restrict__ q, const float* __restrict__ kk,
    const float* __restrict__ adj, const float* __restrict__ dense,
    const float* __restrict__ W1, const float* __restrict__ b1,
    const float* __restrict__ W2, const float* __restrict__ b2,
    const float* __restrict__ W3, const float* __restrict__ b3,
    float* __restrict__ logits)
{
  int t = threadIdx.x;
  int wave = t >> 6;
  int l = t & 63;
  int lj = l & 15, g = l >> 4;
  int j0 = blockIdx.x * 64 + wave * 16;
  int i0 = blockIdx.y * 16;
  int c1b = 8*g;

  // dots = kk @ q^T on this 16x16 tile.  A = kk rows (i), B[k][j] = q[j][k].
  const f32x4* kp = (const f32x4*)(kk + (i0+lj)*32 + c1b);
  f32x4 k0 = kp[0], k1 = kp[1];
  const f32x4* qp = (const f32x4*)(q + (j0+lj)*32 + c1b);
  f32x4 q0 = qp[0], q1 = qp[1];
  bf16x8 af, bq8;
  #pragma unroll
  for (int e=0;e<4;++e){
    af[e] = (__bf16)k0[e];  af[4+e] = (__bf16)k1[e];
    bq8[e] = (__bf16)q0[e]; bq8[4+e] = (__bf16)q1[e];
  }
  f32x4 dacc = {0.f,0.f,0.f,0.f};
  dacc = __builtin_amdgcn_mfma_f32_16x16x32_bf16(af, bq8, dacc, 0, 0, 0);
  // dacc[r] = dots[i0+4g+r][j0+lj]

  // per-lane W1 slices (c1 = 8g .. 8g+7)
  f32x4 w10a = *(const f32x4*)(W1 + c1b);      f32x4 w10b = *(const f32x4*)(W1 + c1b + 4);
  f32x4 w11a = *(const f32x4*)(W1 + 32 + c1b); f32x4 w11b = *(const f32x4*)(W1 + 32 + c1b + 4);
  f32x4 w12a = *(const f32x4*)(W1 + 64 + c1b); f32x4 w12b = *(const f32x4*)(W1 + 64 + c1b + 4);
  f32x4 b1a  = *(const f32x4*)(b1 + c1b);      f32x4 b1b  = *(const f32x4*)(b1 + c1b + 4);
  // A-frags for the swapped W2 MFMA: A = W2^T (m = c2 within half, k = c1)
  bf16x8 w2f0, w2f1;
  #pragma unroll
  for (int e=0;e<8;++e){
    w2f0[e] = (__bf16)W2[(c1b+e)*32 + lj];
    w2f1[e] = (__bf16)W2[(c1b+e)*32 + 16 + lj];
  }
  // per-lane b2/W3 slices for c2 = 4g..4g+3 and 16+4g..16+4g+3
  f32x4 b2lo = *(const f32x4*)(b2 + 4*g);
  f32x4 b2hi = *(const f32x4*)(b2 + 16 + 4*g);
  f32x4 w3lo = *(const f32x4*)(W3 + 4*g);
  f32x4 w3hi = *(const f32x4*)(W3 + 16 + 4*g);
  float b3v = b3[0];

  float adjv[16], denv[16];
  #pragma unroll
  for (int m=0;m<16;++m){
    adjv[m] = adj  [(i0+m)*NN + j0 + lj];
    denv[m] = dense[(i0+m)*NN + j0 + lj];
  }

  #pragma unroll
  for (int m=0;m<16;++m){
    // broadcast dots[i0+m][j0+lj] to all 4 k-groups
    float d = __shfl(dacc[m & 3], ((m >> 2) << 4) + lj, 64);
    // f1 = relu(feats @ W1 + b1): this lane's 8-c1 slice for pair (m, lj)
    bf16x8 f1f;
    #pragma unroll
    for (int e=0;e<4;++e){
      float fa = fmaf(d, w10a[e], fmaf(adjv[m], w11a[e], fmaf(denv[m], w12a[e], b1a[e])));
      f1f[e]   = (__bf16)fmaxf(fa, 0.f);
      float fb = fmaf(d, w10b[e], fmaf(adjv[m], w11b[e], fmaf(denv[m], w12b[e], b1b[e])));
      f1f[4+e] = (__bf16)fmaxf(fb, 0.f);
    }
    f32x4 z = {0.f,0.f,0.f,0.f};
    // D[c2][pair]: lane holds pair lj, c2 = 4g+r (half0) / 16+4g+r (half1)
    f32x4 a0 = __builtin_amdgcn_mfma_f32_16x16x32_bf16(w2f0, f1f, z, 0,0,0);
    f32x4 a1 = __builtin_amdgcn_mfma_f32_16x16x32_bf16(w2f1, f1f, z, 0,0,0);
    float tl = 0.f;
    #pragma unroll
    for (int r=0;r<4;++r){
      tl = fmaf(fmaxf(a0[r]+b2lo[r], 0.f), w3lo[r], tl);
      tl = fmaf(fmaxf(a1[r]+b2hi[r], 0.f), w3hi[r], tl);
    }
    tl += __shfl_xor(tl, 16, 64);
    tl += __shfl_xor(tl, 32, 64);
    tl += b3v;
    if (g == 0) logits[(i0+m)*NN + j0 + lj] = tl;
  }
}

// ---------------- softmax + focus@v + residual (+ fused qkv-next or decode) ----------------
template<int LAST>
__launch_bounds__(256)
__global__ void k_pv(const float* __restrict__ logits,
    const float* __restrict__ v, const float* __restrict__ h_in,
    float* __restrict__ h_out,
    const float* __restrict__ Wq, const float* __restrict__ bq,
    const float* __restrict__ Wk, const float* __restrict__ bk,
    const float* __restrict__ Wv, const float* __restrict__ bv,
    float* __restrict__ qn, float* __restrict__ kn, float* __restrict__ vn,
    const float* __restrict__ Wdec, const float* __restrict__ bdec,
    const float* __restrict__ mask, float* __restrict__ out)
{
  int t = threadIdx.x;
  int w = t >> 6;
  int l = t & 63;
  int li = l & 15, g = l >> 4;
  int i0 = blockIdx.x * 16;
  int jw = w * 512;
  const float* lrow = logits + (i0+li)*NN + jw + 8*g;

  // pre-pass: exact row max (lane-local over its 128 j's, then 2 shfl)
  f32x4 mx4 = {-INFINITY,-INFINITY,-INFINITY,-INFINITY};
  for (int s=0; s<16; ++s){
    f32x4 p0 = *(const f32x4*)(lrow + s*32);
    f32x4 p1 = *(const f32x4*)(lrow + s*32 + 4);
    #pragma unroll
    for (int e=0;e<4;++e){ mx4[e] = fmaxf(mx4[e], p0[e]); mx4[e] = fmaxf(mx4[e], p1[e]); }
  }
  float mxl = fmaxf(fmaxf(mx4[0],mx4[1]), fmaxf(mx4[2],mx4[3]));
  mxl = fmaxf(mxl, __shfl_xor(mxl, 16, 64));
  mxl = fmaxf(mxl, __shfl_xor(mxl, 32, 64));
  __shared__ float Ms[4][16];
  if (l < 16) Ms[w][l] = mxl;
  __syncthreads();
  float Mrow = fmaxf(fmaxf(Ms[0][li],Ms[1][li]), fmaxf(Ms[2][li],Ms[3][li]));

  f32x4 acc0 = {0.f,0.f,0.f,0.f}, acc1 = {0.f,0.f,0.f,0.f};
  float Lp = 0.f;
  for (int s=0; s<16; ++s){
    int jb = jw + s*32 + 8*g;
    f32x4 p0 = *(const f32x4*)(lrow + s*32);
    f32x4 p1 = *(const f32x4*)(lrow + s*32 + 4);
    bf16x8 pf;
    #pragma unroll
    for (int e=0;e<4;++e){
      float e0 = __expf(p0[e] - Mrow);
      __bf16 r0 = (__bf16)e0; pf[e]   = r0; Lp += (float)r0;
      float e1 = __expf(p1[e] - Mrow);
      __bf16 r1 = (__bf16)e1; pf[4+e] = r1; Lp += (float)r1;
    }
    bf16x8 vf0, vf1;
    #pragma unroll
    for (int e=0;e<8;++e){
      vf0[e] = (__bf16)v[(jb+e)*32 + li];
      vf1[e] = (__bf16)v[(jb+e)*32 + 16 + li];
    }
    acc0 = __builtin_amdgcn_mfma_f32_16x16x32_bf16(pf, vf0, acc0, 0,0,0);
    acc1 = __builtin_amdgcn_mfma_f32_16x16x32_bf16(pf, vf1, acc1, 0,0,0);
  }
  Lp += __shfl_xor(Lp, 16, 64);
  Lp += __shfl_xor(Lp, 32, 64);
  __shared__ float accs[4][16][32];
  __shared__ float Ls[4][16];
  __shared__ float hsn[16][32];
  #pragma unroll
  for (int r=0;r<4;++r){
    accs[w][4*g+r][li]    = acc0[r];
    accs[w][4*g+r][16+li] = acc1[r];
  }
  if (l < 16) Ls[w][l] = Lp;
  __syncthreads();
  for (int o = t; o < 512; o += 256){
    int i = o >> 5, c = o & 31;
    float s4 = accs[0][i][c] + accs[1][i][c] + accs[2][i][c] + accs[3][i][c];
    float L4 = Ls[0][i] + Ls[1][i] + Ls[2][i] + Ls[3][i];
    float hnew = h_in[(i0+i)*32 + c] + s4 / L4;
    hsn[i][c] = hnew;
    if (!LAST) h_out[(i0+i)*32+c] = hnew;
  }
  __syncthreads();
  if (!LAST){
    for (int o = t; o < 512; o += 256){
      int i = o >> 5, c = o & 31;
      float aq = bq[c], ak = bk[c], av = bv[c];
      #pragma unroll 8
      for (int d=0; d<32; ++d){
        float hv = hsn[i][d];
        aq = fmaf(hv, Wq[d*32+c], aq);
        ak = fmaf(hv, Wk[d*32+c], ak);
        av = fmaf(hv, Wv[d*32+c], av);
      }
      qn[(i0+i)*32+c] = aq; kn[(i0+i)*32+c] = ak; vn[(i0+i)*32+c] = av;
    }
  } else {
    __shared__ float red[16][16];
    int ii = t >> 4, cs = t & 15;
    float part = hsn[ii][2*cs]*Wdec[2*cs] + hsn[ii][2*cs+1]*Wdec[2*cs+1];
    red[ii][cs] = part;
    __syncthreads();
    if (t < 16){
      float sacc = 0.f;
      #pragma unroll
      for (int e=0;e<16;++e) sacc += red[t][e];
      float o = sacc + bdec[0];
      float mk = mask[i0+t];
      out[i0+t] = o + (mk == 0.f ? -INFINITY : 0.f);
    }
  }
}

extern "C" void kernel_launch(void* const* d_in, const int* in_sizes, int n_in,
                              void* d_out, int out_size, void* d_ws, size_t ws_size,
                              hipStream_t stream)
{
  const float* x     = (const float*)d_in[0];
  const float* comms = (const float*)d_in[1];
  const float* adj   = (const float*)d_in[2];
  const float* dense = (const float*)d_in[3];
  const float* mask  = (const float*)d_in[4];
  const float* Wenc  = (const float*)d_in[5];
  const float* benc  = (const float*)d_in[6];
  const float* Wq    = (const float*)d_in[7];
  const float* bq    = (const float*)d_in[8];
  const float* Wk    = (const float*)d_in[9];
  const float* bk    = (const float*)d_in[10];
  const float* Wv    = (const float*)d_in[11];
  const float* bv    = (const float*)d_in[12];
  const float* W1    = (const float*)d_in[13];
  const float* b1    = (const float*)d_in[14];
  const float* W2    = (const float*)d_in[15];
  const float* b2    = (const float*)d_in[16];
  const float* W3    = (const float*)d_in[17];
  const float* b3    = (const float*)d_in[18];
  const float* Wdec  = (const float*)d_in[19];
  const float* bdec  = (const float*)d_in[20];
  float* out = (float*)d_out;

  float* logits = (float*)d_ws;
  float* h1 = logits + (size_t)NN*NN;
  float* h2 = h1 + NN*32;
  float* q1 = h2 + NN*32;
  float* k1 = q1 + NN*32;
  float* v1 = k1 + NN*32;
  float* q2 = v1 + NN*32;
  float* k2 = q2 + NN*32;
  float* v2 = k2 + NN*32;

  k_encqkv<<<256, 256, 0, stream>>>(x, comms, Wenc, benc, Wq,bq,Wk,bk,Wv,bv,
                                    h1, q1, k1, v1);
  dim3 gl(32, 128);
  k_logits<<<gl, 256, 0, stream>>>(q1, k1, adj, dense, W1,b1,W2,b2,W3,b3, logits);
  k_pv<0><<<128, 256, 0, stream>>>(logits, v1, h1, h2,
                                   Wq,bq,Wk,bk,Wv,bv, q2,k2,v2,
                                   nullptr, nullptr, nullptr, nullptr);
  k_logits<<<gl, 256, 0, stream>>>(q2, k2, adj, dense, W1,b1,W2,b2,W3,b3, logits);
  k_pv<1><<<128, 256, 0, stream>>>(logits, v2, h2, nullptr,
                                   nullptr,nullptr,nullptr,nullptr,nullptr,nullptr,
                                   nullptr,nullptr,nullptr,
                                   Wdec, bdec, mask, out);
}